// Round 9
// baseline (736.127 us; speedup 1.0000x reference)
//
#include <hip/hip_runtime.h>
#include <hip/hip_bf16.h>

#define NN 65536
#define SS 128
#define CC 128
#define EE 262144
#define BB 512
#define LL 3
#define NREP 64

typedef __attribute__((ext_vector_type(8))) short bf16x8;
typedef __attribute__((ext_vector_type(4))) float f32x4;

__device__ __forceinline__ float b2f(unsigned short u) {
    union { unsigned int i; float f; } x; x.i = ((unsigned int)u) << 16; return x.f;
}
__device__ __forceinline__ unsigned short f2b(float f) {
    union { float f; unsigned int i; } x; x.f = f;
    unsigned int r = x.i + 0x7fffu + ((x.i >> 16) & 1u);
    return (unsigned short)(r >> 16);
}
// swizzled byte offset within a tile of row-stride ROWB bytes
#define SWB(row, colbyte, ROWB) ((row) * (ROWB) + ((colbyte) ^ (((row) & 7) << 4)))

// ================= CSR build =================
__global__ __launch_bounds__(256) void hist_k(const int* __restrict__ eidx, int* __restrict__ cnt) {
    const int e = blockIdx.x * 256 + threadIdx.x;
    atomicAdd(&cnt[eidx[EE + e]], 1);
}
__global__ __launch_bounds__(256) void scan1_k(const int* __restrict__ cnt, int* __restrict__ row,
                                               int* __restrict__ part) {
    __shared__ int s[256];
    const int tid = threadIdx.x;
    const int i = blockIdx.x * 256 + tid;
    const int v = cnt[i];
    s[tid] = v;
    __syncthreads();
    for (int off = 1; off < 256; off <<= 1) {
        int t = (tid >= off) ? s[tid - off] : 0;
        __syncthreads(); s[tid] += t; __syncthreads();
    }
    row[i] = s[tid] - v;
    if (tid == 255) part[blockIdx.x] = s[255];
}
__global__ __launch_bounds__(256) void scan2_k(int* __restrict__ part) {
    __shared__ int s[256];
    const int tid = threadIdx.x;
    const int v = part[tid];
    s[tid] = v;
    __syncthreads();
    for (int off = 1; off < 256; off <<= 1) {
        int t = (tid >= off) ? s[tid - off] : 0;
        __syncthreads(); s[tid] += t; __syncthreads();
    }
    part[tid] = s[tid] - v;
}
__global__ __launch_bounds__(256) void scan3_k(int* __restrict__ row, const int* __restrict__ part) {
    const int i = blockIdx.x * 256 + threadIdx.x;
    row[i] += part[blockIdx.x];
    if (i == 0) row[NN] = EE;
}
__global__ __launch_bounds__(256) void fill_k(const int* __restrict__ eidx, const int* __restrict__ row,
                                              int* __restrict__ cnt, int* __restrict__ elist) {
    const int e = blockIdx.x * 256 + threadIdx.x;
    const int d = eidx[EE + e];
    const int slot = row[d] + atomicAdd(&cnt[d], 1);
    elist[slot] = e;
}

// ================= weight convert + transpose to bf16 WT[N][K] =================
__global__ __launch_bounds__(256) void cvtw(const float* __restrict__ gW1, const float* __restrict__ gW2,
                                            const float* __restrict__ inW, const float* __restrict__ oW,
                                            const float* __restrict__ mW1, const float* __restrict__ mW2,
                                            unsigned short* __restrict__ WB) {
    const int g = blockIdx.x * 256 + threadIdx.x;  // 0 .. 3*163840
    const int l = g / 163840;
    const int r = g % 163840;
    const float* src; int K, Nc, dst, i;
    if (r < 16384)       { src = gW1 + l * 16384; K = 128; Nc = 128; dst = 0;      i = r; }
    else if (r < 32768)  { src = gW2 + l * 16384; K = 128; Nc = 128; dst = 16384;  i = r - 16384; }
    else if (r < 81920)  { src = inW + l * 49152; K = 128; Nc = 384; dst = 32768;  i = r - 32768; }
    else if (r < 98304)  { src = oW  + l * 16384; K = 128; Nc = 128; dst = 81920;  i = r - 81920; }
    else if (r < 131072) { src = mW1 + l * 32768; K = 128; Nc = 256; dst = 98304;  i = r - 98304; }
    else                 { src = mW2 + l * 32768; K = 256; Nc = 128; dst = 131072; i = r - 131072; }
    const int k = i / Nc, c = i % Nc;
    WB[(size_t)l * 163840 + dst + (size_t)c * K + k] = f2b(src[i]);
}

// ================= pe column stats: one row per thread =================
__global__ __launch_bounds__(256) void colstats_pe(const float* __restrict__ pe,
                                                   float* __restrict__ stats) {
    const int r = blockIdx.x * 256 + threadIdx.x;
    const float* p = pe + (size_t)r * 20;
    float v[20];
    *(float4*)&v[0]  = *(const float4*)(p);
    *(float4*)&v[4]  = *(const float4*)(p + 4);
    *(float4*)&v[8]  = *(const float4*)(p + 8);
    *(float4*)&v[12] = *(const float4*)(p + 12);
    *(float4*)&v[16] = *(const float4*)(p + 16);
    float s[20], q[20];
#pragma unroll
    for (int i = 0; i < 20; ++i) { s[i] = v[i]; q[i] = v[i] * v[i]; }
#pragma unroll
    for (int off = 1; off < 64; off <<= 1) {
#pragma unroll
        for (int i = 0; i < 20; ++i) {
            s[i] += __shfl_xor(s[i], off);
            q[i] += __shfl_xor(q[i], off);
        }
    }
    __shared__ float red[4][40];
    const int lane = threadIdx.x & 63, w = threadIdx.x >> 6;
    if (lane == 0) {
#pragma unroll
        for (int i = 0; i < 20; ++i) { red[w][i] = s[i]; red[w][20 + i] = q[i]; }
    }
    __syncthreads();
    if (threadIdx.x < 40) {
        const float t = red[0][threadIdx.x] + red[1][threadIdx.x] +
                        red[2][threadIdx.x] + red[3][threadIdx.x];
        atomicAdd(&stats[threadIdx.x], t);
    }
}

// ================= BN helpers =================
// stats layout: nrep replicas of [sum[ncols] | sumsq[ncols]]
__global__ void bn_finalize(const float* __restrict__ stats, const float* __restrict__ g,
                            const float* __restrict__ b, float* __restrict__ scoff,
                            int ncols, float invn, int nrep) {
    const int c = threadIdx.x;
    if (c < ncols) {
        float s = 0.f, q = 0.f;
#pragma unroll 8
        for (int r = 0; r < nrep; ++r) {
            s += stats[r * 2 * ncols + c];
            q += stats[r * 2 * ncols + ncols + c];
        }
        float m = s * invn;
        float var = q * invn - m * m;
        float rs = rsqrtf(var + 1e-5f);
        float sc = g[c] * rs;
        scoff[c] = sc;
        scoff[ncols + c] = b[c] - m * sc;
    }
}
// XB (bf16) <- bn(Z f32)
__global__ __launch_bounds__(256) void bn_apply_b(const float* __restrict__ in,
                                                  const float* __restrict__ scoff,
                                                  unsigned short* __restrict__ out) {
    const size_t g = (size_t)blockIdx.x * 256 + threadIdx.x;  // N*16
    const int c8 = ((int)g & 15) << 3;
    float4 a0 = *(const float4*)(in + g * 8);
    float4 a1 = *(const float4*)(in + g * 8 + 4);
    float v[8] = {a0.x, a0.y, a0.z, a0.w, a1.x, a1.y, a1.z, a1.w};
    union { uint4 u; unsigned short s[8]; } o;
#pragma unroll
    for (int i = 0; i < 8; ++i) o.s[i] = f2b(v[i] * scoff[c8 + i] + scoff[128 + c8 + i]);
    *(uint4*)(out + g * 8) = o.u;
}
// d_out (f32) <- bn(Z f32)
__global__ __launch_bounds__(256) void bn_apply_f(const float* __restrict__ in,
                                                  const float* __restrict__ scoff,
                                                  float* __restrict__ out) {
    const size_t g = (size_t)blockIdx.x * 256 + threadIdx.x;
    const int c8 = ((int)g & 15) << 3;
    float4 a0 = *(const float4*)(in + g * 8);
    float4 a1 = *(const float4*)(in + g * 8 + 4);
    float v[8] = {a0.x, a0.y, a0.z, a0.w, a1.x, a1.y, a1.z, a1.w};
    float4 o0, o1;
    o0.x = v[0] * scoff[c8 + 0] + scoff[128 + c8 + 0];
    o0.y = v[1] * scoff[c8 + 1] + scoff[128 + c8 + 1];
    o0.z = v[2] * scoff[c8 + 2] + scoff[128 + c8 + 2];
    o0.w = v[3] * scoff[c8 + 3] + scoff[128 + c8 + 3];
    o1.x = v[4] * scoff[c8 + 4] + scoff[128 + c8 + 4];
    o1.y = v[5] * scoff[c8 + 5] + scoff[128 + c8 + 5];
    o1.z = v[6] * scoff[c8 + 6] + scoff[128 + c8 + 6];
    o1.w = v[7] * scoff[c8 + 7] + scoff[128 + c8 + 7];
    *(float4*)(out + g * 8) = o0;
    *(float4*)(out + g * 8 + 4) = o1;
}
// OUT(bf16) = bn1(Z f32) + bn2(HA f32)
__global__ __launch_bounds__(256) void combine2(const float* __restrict__ z,
                                                const float* __restrict__ ha,
                                                const float* __restrict__ scoff,
                                                unsigned short* __restrict__ out) {
    const size_t g = (size_t)blockIdx.x * 256 + threadIdx.x;
    const int c8 = ((int)g & 15) << 3;
    float4 a0 = *(const float4*)(z + g * 8);
    float4 a1 = *(const float4*)(z + g * 8 + 4);
    float4 b0 = *(const float4*)(ha + g * 8);
    float4 b1 = *(const float4*)(ha + g * 8 + 4);
    float va[8] = {a0.x, a0.y, a0.z, a0.w, a1.x, a1.y, a1.z, a1.w};
    float vb[8] = {b0.x, b0.y, b0.z, b0.w, b1.x, b1.y, b1.z, b1.w};
    union { uint4 u; unsigned short s[8]; } o;
#pragma unroll
    for (int i = 0; i < 8; ++i) {
        const int c = c8 + i;
        o.s[i] = f2b(va[i] * scoff[c] + scoff[128 + c] +
                     vb[i] * scoff[256 + c] + scoff[384 + c]);
    }
    *(uint4*)(out + g * 8) = o.u;
}

// ================= input featurization -> XB bf16 =================
__global__ __launch_bounds__(256) void embed_b(const int* __restrict__ node_type,
                                               const float* __restrict__ pe,
                                               const float* __restrict__ scoff,
                                               const float* __restrict__ peW,
                                               const float* __restrict__ peB,
                                               const float* __restrict__ node_emb,
                                               unsigned short* __restrict__ XB) {
    const int g = blockIdx.x * 256 + threadIdx.x;  // N*16
    const int n = g >> 4, c8 = (g & 15) << 3;
    float v[8];
    if (c8 < 120) {
        const float4 a = *(const float4*)(node_emb + (size_t)node_type[n] * 120 + c8);
        const float4 b = *(const float4*)(node_emb + (size_t)node_type[n] * 120 + c8 + 4);
        v[0] = a.x; v[1] = a.y; v[2] = a.z; v[3] = a.w;
        v[4] = b.x; v[5] = b.y; v[6] = b.z; v[7] = b.w;
    } else {
#pragma unroll
        for (int j = 0; j < 8; ++j) v[j] = peB[j];
#pragma unroll
        for (int k = 0; k < 20; ++k) {
            const float p = pe[(size_t)n * 20 + k] * scoff[k] + scoff[20 + k];
#pragma unroll
            for (int j = 0; j < 8; ++j) v[j] = fmaf(p, peW[k * 8 + j], v[j]);
        }
    }
    union { uint4 u; unsigned short s[8]; } o;
#pragma unroll
    for (int i = 0; i < 8; ++i) o.s[i] = f2b(v[i]);
    *(uint4*)(XB + (size_t)g * 8) = o.u;
}

// ====== fused GINE: gather + t1=relu(z@W1+b1) + h_pre=t1@W2+b2+X -> f32 + stats ======
// Block = 128 rows, 4 waves. LDS 64KB: slotB (B1 then B2, 32KB swz) | slotT (t1, 32KB swz);
// f32 output staged across full 64KB after MFMA2, then streamed coalesced.
__global__ __launch_bounds__(256) void gine_fused(const unsigned short* __restrict__ XB,
                                                  const int* __restrict__ eidx,
                                                  const int* __restrict__ etype,
                                                  const float* __restrict__ edge_emb,
                                                  const int* __restrict__ irow,
                                                  const int* __restrict__ elist,
                                                  const unsigned short* __restrict__ W1T,
                                                  const float* __restrict__ b1,
                                                  const unsigned short* __restrict__ W2T,
                                                  const float* __restrict__ b2,
                                                  float* __restrict__ outp,
                                                  float* __restrict__ stats) {
    extern __shared__ __align__(16) char LDSX[];
    char* slotB = LDSX;            // 32KB: B1, later B2
    char* slotT = LDSX + 32768;    // 32KB: t1 tile
    const int tid = threadIdx.x, lane = tid & 63, w = tid >> 6;
    const int lr = lane & 15, lg = lane >> 4;
    const int bm = blockIdx.x * 128;

    // ---- stage B1 = W1T[128][128] swizzled ----
#pragma unroll
    for (int i = 0; i < 8; ++i) {
        const int c = (i * 256 + tid) * 16;
        const int row = c >> 8, inrow = c & 255;
        *(uint4*)(slotB + SWB(row, inrow, 256)) = *(const uint4*)(W1T + (size_t)row * 128 + (inrow >> 1));
    }
    // ---- A-build (gather): z = x + sum relu(x[src]+ee) for rows w*32+r*16+lr ----
    bf16x8 af1[2][4];
#pragma unroll
    for (int r = 0; r < 2; ++r) {
        const int row = bm + w * 32 + r * 16 + lr;
        float z[4][8];
#pragma unroll
        for (int ks = 0; ks < 4; ++ks) {
            union { uint4 u; unsigned short s[8]; } xv;
            xv.u = *(const uint4*)(XB + (size_t)row * 128 + ks * 32 + lg * 8);
#pragma unroll
            for (int i = 0; i < 8; ++i) z[ks][i] = b2f(xv.s[i]);
        }
        const int beg = irow[row], end = irow[row + 1];
        for (int j = beg; j < end; ++j) {
            const int e = elist[j];
            const int src = eidx[e];
            const int et = etype[e];
#pragma unroll
            for (int ks = 0; ks < 4; ++ks) {
                union { uint4 u; unsigned short s[8]; } xs;
                xs.u = *(const uint4*)(XB + (size_t)src * 128 + ks * 32 + lg * 8);
                const float4 e0 = *(const float4*)(edge_emb + (size_t)et * 128 + ks * 32 + lg * 8);
                const float4 e1 = *(const float4*)(edge_emb + (size_t)et * 128 + ks * 32 + lg * 8 + 4);
                z[ks][0] += fmaxf(b2f(xs.s[0]) + e0.x, 0.f);
                z[ks][1] += fmaxf(b2f(xs.s[1]) + e0.y, 0.f);
                z[ks][2] += fmaxf(b2f(xs.s[2]) + e0.z, 0.f);
                z[ks][3] += fmaxf(b2f(xs.s[3]) + e0.w, 0.f);
                z[ks][4] += fmaxf(b2f(xs.s[4]) + e1.x, 0.f);
                z[ks][5] += fmaxf(b2f(xs.s[5]) + e1.y, 0.f);
                z[ks][6] += fmaxf(b2f(xs.s[6]) + e1.z, 0.f);
                z[ks][7] += fmaxf(b2f(xs.s[7]) + e1.w, 0.f);
            }
        }
#pragma unroll
        for (int ks = 0; ks < 4; ++ks) {
            union { bf16x8 v; unsigned short s[8]; } o;
#pragma unroll
            for (int i = 0; i < 8; ++i) o.s[i] = f2b(z[ks][i]);
            af1[r][ks] = o.v;
        }
    }
    float bc1[8];
#pragma unroll
    for (int nt = 0; nt < 8; ++nt) bc1[nt] = b1[nt * 16 + lr];
    __syncthreads();

    // ---- MFMA1: acc = z @ W1^T ----
    f32x4 acc[2][8];
#pragma unroll
    for (int r = 0; r < 2; ++r)
#pragma unroll
        for (int nt = 0; nt < 8; ++nt) acc[r][nt] = (f32x4){0.f, 0.f, 0.f, 0.f};
#pragma unroll
    for (int ks = 0; ks < 4; ++ks) {
        bf16x8 bq[8];
#pragma unroll
        for (int nt = 0; nt < 8; ++nt)
            bq[nt] = *(const bf16x8*)(slotB + SWB(nt * 16 + lr, ks * 64 + lg * 16, 256));
#pragma unroll
        for (int r = 0; r < 2; ++r)
#pragma unroll
            for (int nt = 0; nt < 8; ++nt)
                acc[r][nt] = __builtin_amdgcn_mfma_f32_16x16x32_bf16(af1[r][ks], bq[nt], acc[r][nt], 0, 0, 0);
    }
    // ---- t1 = relu(acc+b1) -> slotT (wave-private rows; no cross-wave dep) ----
#pragma unroll
    for (int r = 0; r < 2; ++r)
#pragma unroll
        for (int nt = 0; nt < 8; ++nt)
#pragma unroll
            for (int j = 0; j < 4; ++j) {
                const float v = fmaxf(acc[r][nt][j] + bc1[nt], 0.f);
                *(unsigned short*)(slotT + SWB(w * 32 + r * 16 + lg * 4 + j, (nt * 16 + lr) * 2, 256)) = f2b(v);
            }
    __syncthreads();  // all waves done reading B1
    // ---- stage B2 = W2T, read t1 fragments ----
#pragma unroll
    for (int i = 0; i < 8; ++i) {
        const int c = (i * 256 + tid) * 16;
        const int row = c >> 8, inrow = c & 255;
        *(uint4*)(slotB + SWB(row, inrow, 256)) = *(const uint4*)(W2T + (size_t)row * 128 + (inrow >> 1));
    }
    bf16x8 af2[2][4];
#pragma unroll
    for (int r = 0; r < 2; ++r)
#pragma unroll
        for (int ks = 0; ks < 4; ++ks)
            af2[r][ks] = *(const bf16x8*)(slotT + SWB(w * 32 + r * 16 + lr, ks * 64 + lg * 16, 256));
    float bc2[8];
#pragma unroll
    for (int nt = 0; nt < 8; ++nt) bc2[nt] = b2[nt * 16 + lr];
    __syncthreads();

    // ---- MFMA2: acc = t1 @ W2^T ----
#pragma unroll
    for (int r = 0; r < 2; ++r)
#pragma unroll
        for (int nt = 0; nt < 8; ++nt) acc[r][nt] = (f32x4){0.f, 0.f, 0.f, 0.f};
#pragma unroll
    for (int ks = 0; ks < 4; ++ks) {
        bf16x8 bq[8];
#pragma unroll
        for (int nt = 0; nt < 8; ++nt)
            bq[nt] = *(const bf16x8*)(slotB + SWB(nt * 16 + lr, ks * 64 + lg * 16, 256));
#pragma unroll
        for (int r = 0; r < 2; ++r)
#pragma unroll
            for (int nt = 0; nt < 8; ++nt)
                acc[r][nt] = __builtin_amdgcn_mfma_f32_16x16x32_bf16(af2[r][ks], bq[nt], acc[r][nt], 0, 0, 0);
    }
    __syncthreads();  // B2 & t1 dead -> full 64KB becomes f32 out-stage

    // ---- stage f32 out [128][128] ----
#pragma unroll
    for (int r = 0; r < 2; ++r)
#pragma unroll
        for (int nt = 0; nt < 8; ++nt)
#pragma unroll
            for (int j = 0; j < 4; ++j)
                ((float*)LDSX)[(w * 32 + r * 16 + lg * 4 + j) * 128 + nt * 16 + lr] = acc[r][nt][j] + bc2[nt];
    __syncthreads();

    // ---- coalesced stream + resid(XB) + stats ----
    float ssum[4] = {0.f, 0.f, 0.f, 0.f}, ssq[4] = {0.f, 0.f, 0.f, 0.f};
#pragma unroll
    for (int i = 0; i < 16; ++i) {
        const int L = (i * 256 + tid) * 16;
        const int row = L >> 9, col = (L & 511) >> 2;
        float4 v = *(const float4*)(LDSX + L);
        const uint2 rv = *(const uint2*)(XB + (size_t)(bm + row) * 128 + col);
        v.x += b2f((unsigned short)(rv.x & 0xffffu));
        v.y += b2f((unsigned short)(rv.x >> 16));
        v.z += b2f((unsigned short)(rv.y & 0xffffu));
        v.w += b2f((unsigned short)(rv.y >> 16));
        ssum[0] += v.x; ssq[0] += v.x * v.x;
        ssum[1] += v.y; ssq[1] += v.y * v.y;
        ssum[2] += v.z; ssq[2] += v.z * v.z;
        ssum[3] += v.w; ssq[3] += v.w * v.w;
        *(float4*)(outp + (size_t)(bm + row) * 128 + col) = v;
    }
#pragma unroll
    for (int c2 = 0; c2 < 4; ++c2) {
        ssum[c2] += __shfl_xor(ssum[c2], 32);
        ssq[c2]  += __shfl_xor(ssq[c2], 32);
    }
    if (lane < 32) {
        float* st = stats + (size_t)(blockIdx.x & (NREP - 1)) * 256;
        const int c0 = (lane & 31) * 4;
#pragma unroll
        for (int c2 = 0; c2 < 4; ++c2) {
            atomicAdd(&st[c0 + c2], ssum[c2]);
            atomicAdd(&st[128 + c0 + c2], ssq[c2]);
        }
    }
}

// ====== LDS-store GEMM: out[M,Nw] = act(A[M,K] @ WT[Nw,K]^T + bias [+resid]) ======
template <int RELU, int RESID, int STATS, int KS, int OUTF>
__global__ __launch_bounds__(256) void gemm_ls(const unsigned short* __restrict__ A,
                                               const unsigned short* __restrict__ WT,
                                               const float* __restrict__ bias,
                                               const unsigned short* __restrict__ resid,
                                               void* __restrict__ outp,
                                               float* __restrict__ stats, int Nw) {
    extern __shared__ __align__(16) char LDSX[];
    const int K = KS * 32;
    const int ROWB = K * 2;
    const int tid = threadIdx.x, lane = tid & 63, w = tid >> 6;
    const int lr = lane & 15, lg = lane >> 4;
    const int bm = blockIdx.x * 128;
    const int bn = blockIdx.y * 128;

    // ---- stage B (WT rows bn..bn+127) into LDS, swizzled ----
#pragma unroll
    for (int i = 0; i < K / 16; ++i) {
        const int c = (i * 256 + tid) * 16;  // byte cursor
        const int row = c / ROWB, inrow = c % ROWB;
        *(uint4*)(LDSX + SWB(row, inrow, ROWB)) =
            *(const uint4*)(WT + (size_t)(bn + row) * K + (inrow >> 1));
    }
    // ---- A fragments ----
    bf16x8 af[2][KS];
#pragma unroll
    for (int r = 0; r < 2; ++r)
#pragma unroll
        for (int ks = 0; ks < KS; ++ks)
            af[r][ks] = *(const bf16x8*)(A + (size_t)(bm + w * 32 + r * 16 + lr) * K + ks * 32 + lg * 8);
    float bcol[8];
#pragma unroll
    for (int nt = 0; nt < 8; ++nt) bcol[nt] = bias[bn + nt * 16 + lr];
    __syncthreads();

    // ---- MFMA ----
    f32x4 acc[2][8];
#pragma unroll
    for (int r = 0; r < 2; ++r)
#pragma unroll
        for (int nt = 0; nt < 8; ++nt) acc[r][nt] = (f32x4){0.f, 0.f, 0.f, 0.f};
#pragma unroll
    for (int ks = 0; ks < KS; ++ks) {
        bf16x8 bq[8];
#pragma unroll
        for (int nt = 0; nt < 8; ++nt)
            bq[nt] = *(const bf16x8*)(LDSX + SWB(nt * 16 + lr, ks * 64 + lg * 16, ROWB));
#pragma unroll
        for (int r = 0; r < 2; ++r)
#pragma unroll
            for (int nt = 0; nt < 8; ++nt)
                acc[r][nt] = __builtin_amdgcn_mfma_f32_16x16x32_bf16(af[r][ks], bq[nt], acc[r][nt], 0, 0, 0);
    }
    __syncthreads();  // B dead; reuse LDS as output staging tile

    // ---- phase 1: acc -> LDS ----
#pragma unroll
    for (int r = 0; r < 2; ++r)
#pragma unroll
        for (int nt = 0; nt < 8; ++nt)
#pragma unroll
            for (int j = 0; j < 4; ++j) {
                float v = acc[r][nt][j] + bcol[nt];
                if (RELU) v = fmaxf(v, 0.f);
                const int rl = w * 32 + r * 16 + lg * 4 + j;
                const int col = nt * 16 + lr;
                if (OUTF) ((float*)LDSX)[rl * 128 + col] = v;
                else ((unsigned short*)LDSX)[rl * 128 + col] = f2b(v);
            }
    __syncthreads();

    // ---- phase 2: coalesced streaming store (+resid +stats) ----
    if (OUTF) {
        float ssum[4] = {0.f, 0.f, 0.f, 0.f}, ssq[4] = {0.f, 0.f, 0.f, 0.f};
#pragma unroll
        for (int i = 0; i < 16; ++i) {
            const int L = (i * 256 + tid) * 16;
            const int row = L >> 9, col = (L & 511) >> 2;
            float4 v = *(const float4*)(LDSX + L);
            if (RESID) {
                const uint2 rv = *(const uint2*)(resid + (size_t)(bm + row) * Nw + bn + col);
                v.x += b2f((unsigned short)(rv.x & 0xffffu));
                v.y += b2f((unsigned short)(rv.x >> 16));
                v.z += b2f((unsigned short)(rv.y & 0xffffu));
                v.w += b2f((unsigned short)(rv.y >> 16));
            }
            if (STATS) {
                ssum[0] += v.x; ssq[0] += v.x * v.x;
                ssum[1] += v.y; ssq[1] += v.y * v.y;
                ssum[2] += v.z; ssq[2] += v.z * v.z;
                ssum[3] += v.w; ssq[3] += v.w * v.w;
            }
            *(float4*)((float*)outp + (size_t)(bm + row) * Nw + bn + col) = v;
        }
        if (STATS) {
#pragma unroll
            for (int c2 = 0; c2 < 4; ++c2) {
                ssum[c2] += __shfl_xor(ssum[c2], 32);
                ssq[c2]  += __shfl_xor(ssq[c2], 32);
            }
            if (lane < 32) {
                float* st = stats + (size_t)(blockIdx.x & (NREP - 1)) * 256;
                const int c0 = (lane & 31) * 4;
#pragma unroll
                for (int c2 = 0; c2 < 4; ++c2) {
                    atomicAdd(&st[c0 + c2], ssum[c2]);
                    atomicAdd(&st[128 + c0 + c2], ssq[c2]);
                }
            }
        }
    } else {
#pragma unroll
        for (int i = 0; i < 8; ++i) {
            const int L = (i * 256 + tid) * 16;
            const int row = L >> 8, colb = L & 255;
            *(uint4*)((char*)outp + ((size_t)(bm + row) * Nw + bn) * 2 + colb) = *(const uint4*)(LDSX + L);
        }
    }
}

// ================= MFMA attention, one block per (graph, head) =================
__global__ __launch_bounds__(256) void attn_mfma(const unsigned short* __restrict__ R,
                                                 unsigned short* __restrict__ O) {
    __shared__ __align__(16) unsigned short SH[128 * 128];  // Q|K -> P -> O-stage
    __shared__ __align__(16) unsigned short Vp[128 * 72];   // V padded rows (144B)
    __shared__ float inv[128];
    const int b = blockIdx.x >> 1, h = blockIdx.x & 1;
    const int tid = threadIdx.x, lane = tid & 63, w = tid >> 6;
    const int lr = lane & 15, lg = lane >> 4;
    unsigned short* Qs = SH;
    unsigned short* Ks = SH + 128 * 64;
    const size_t rb = (size_t)b * 128 * 384 + h * 64;
#pragma unroll
    for (int i = 0; i < 4; ++i) {
        const int f = tid + i * 256;  // 0..1023
        const int r = f >> 3, ch = f & 7;
        *(uint4*)((char*)Qs + SWB(r, ch * 16, 128)) = *(const uint4*)(R + rb + (size_t)r * 384 + ch * 8);
        *(uint4*)((char*)Ks + SWB(r, ch * 16, 128)) = *(const uint4*)(R + rb + (size_t)r * 384 + 128 + ch * 8);
        *(uint4*)((char*)Vp + r * 144 + ch * 16) = *(const uint4*)(R + rb + (size_t)r * 384 + 256 + ch * 8);
    }
    __syncthreads();
    f32x4 s[8][2];
#pragma unroll
    for (int m = 0; m < 8; ++m)
#pragma unroll
        for (int n = 0; n < 2; ++n) s[m][n] = (f32x4){0.f, 0.f, 0.f, 0.f};
#pragma unroll
    for (int kd = 0; kd < 2; ++kd) {
        bf16x8 ak[8], bq[2];
#pragma unroll
        for (int m = 0; m < 8; ++m)
            ak[m] = *(const bf16x8*)((const char*)Ks + SWB(m * 16 + lr, kd * 64 + lg * 16, 128));
#pragma unroll
        for (int n = 0; n < 2; ++n)
            bq[n] = *(const bf16x8*)((const char*)Qs + SWB(w * 32 + n * 16 + lr, kd * 64 + lg * 16, 128));
#pragma unroll
        for (int m = 0; m < 8; ++m)
#pragma unroll
            for (int n = 0; n < 2; ++n)
                s[m][n] = __builtin_amdgcn_mfma_f32_16x16x32_bf16(ak[m], bq[n], s[m][n], 0, 0, 0);
    }
    const float SC = 0.125f * 1.44269504f;
#pragma unroll
    for (int n = 0; n < 2; ++n) {
        float mx = -1e30f;
#pragma unroll
        for (int m = 0; m < 8; ++m)
#pragma unroll
            for (int j = 0; j < 4; ++j) { s[m][n][j] *= SC; mx = fmaxf(mx, s[m][n][j]); }
        mx = fmaxf(mx, __shfl_xor(mx, 16));
        mx = fmaxf(mx, __shfl_xor(mx, 32));
        float sum = 0.f;
#pragma unroll
        for (int m = 0; m < 8; ++m)
#pragma unroll
            for (int j = 0; j < 4; ++j) {
                const float p = exp2f(s[m][n][j] - mx);
                s[m][n][j] = p;
                sum += p;
            }
        sum += __shfl_xor(sum, 16);
        sum += __shfl_xor(sum, 32);
        if (lg == 0) inv[w * 32 + n * 16 + lr] = 1.0f / sum;
    }
    __syncthreads();
#pragma unroll
    for (int n = 0; n < 2; ++n) {
        const int q = w * 32 + n * 16 + lr;
#pragma unroll
        for (int m = 0; m < 8; ++m) {
            ushort4 pk;
            pk.x = f2b(s[m][n][0]); pk.y = f2b(s[m][n][1]);
            pk.z = f2b(s[m][n][2]); pk.w = f2b(s[m][n][3]);
            *(ushort4*)((char*)SH + SWB(q, (m * 16 + lg * 4) * 2, 256)) = pk;
        }
    }
    __syncthreads();
    f32x4 o[2][4];
#pragma unroll
    for (int m = 0; m < 2; ++m)
#pragma unroll
        for (int n = 0; n < 4; ++n) o[m][n] = (f32x4){0.f, 0.f, 0.f, 0.f};
#pragma unroll
    for (int ks = 0; ks < 4; ++ks) {
        bf16x8 ap[2], bv[4];
#pragma unroll
        for (int m = 0; m < 2; ++m)
            ap[m] = *(const bf16x8*)((const char*)SH + SWB(w * 32 + m * 16 + lr, ks * 64 + lg * 16, 256));
#pragma unroll
        for (int n = 0; n < 4; ++n) {
            union { bf16x8 v; unsigned short u[8]; } t;
#pragma unroll
            for (int i = 0; i < 8; ++i) t.u[i] = Vp[(ks * 32 + lg * 8 + i) * 72 + n * 16 + lr];
            bv[n] = t.v;
        }
#pragma unroll
        for (int m = 0; m < 2; ++m)
#pragma unroll
            for (int n = 0; n < 4; ++n)
                o[m][n] = __builtin_amdgcn_mfma_f32_16x16x32_bf16(ap[m], bv[n], o[m][n], 0, 0, 0);
    }
    __syncthreads();  // done reading P; reuse SH head as O-stage [128][64]
    unsigned short* Os = SH;
#pragma unroll
    for (int m = 0; m < 2; ++m)
#pragma unroll
        for (int j = 0; j < 4; ++j) {
            const int q = w * 32 + m * 16 + lg * 4 + j;
            const float sc = inv[q];
#pragma unroll
            for (int n = 0; n < 4; ++n)
                Os[q * 64 + n * 16 + lr] = f2b(o[m][n][j] * sc);
        }
    __syncthreads();
#pragma unroll
    for (int i = 0; i < 4; ++i) {
        const int L = (i * 256 + tid) * 16;
        const int row = L >> 7, colb = L & 127;
        *(uint4*)((char*)O + ((size_t)(b * 128 + row) * 128 + h * 64) * 2 + colb) =
            *(const uint4*)((const char*)Os + L);
    }
}

extern "C" void kernel_launch(void* const* d_in, const int* in_sizes, int n_in,
                              void* d_out, int out_size, void* d_ws, size_t ws_size,
                              hipStream_t stream) {
    const int* node_type = (const int*)d_in[0];
    const float* pe = (const float*)d_in[1];
    const int* eidx = (const int*)d_in[2];
    const int* etype = (const int*)d_in[3];
    const float* pe_gamma = (const float*)d_in[5];
    const float* pe_beta = (const float*)d_in[6];
    const float* pe_W = (const float*)d_in[7];
    const float* pe_b = (const float*)d_in[8];
    const float* node_emb = (const float*)d_in[9];
    const float* edge_emb = (const float*)d_in[10];
    const float* gine_W1 = (const float*)d_in[11];
    const float* gine_b1 = (const float*)d_in[12];
    const float* gine_W2 = (const float*)d_in[13];
    const float* gine_b2 = (const float*)d_in[14];
    const float* n1_g = (const float*)d_in[15];
    const float* n1_b = (const float*)d_in[16];
    const float* n2_g = (const float*)d_in[17];
    const float* n2_b = (const float*)d_in[18];
    const float* n3_g = (const float*)d_in[19];
    const float* n3_b = (const float*)d_in[20];
    const float* attn_inW = (const float*)d_in[21];
    const float* attn_inb = (const float*)d_in[22];
    const float* attn_outW = (const float*)d_in[23];
    const float* attn_outb = (const float*)d_in[24];
    const float* mlp_W1 = (const float*)d_in[25];
    const float* mlp_b1 = (const float*)d_in[26];
    const float* mlp_W2 = (const float*)d_in[27];
    const float* mlp_b2 = (const float*)d_in[28];

    const size_t NC = (size_t)NN * CC;
    unsigned short* XB = (unsigned short*)d_ws;      // [N,128] bf16 backbone
    unsigned short* Zb = XB + NC;                    // [N,128] (unused, kept for layout)
    unsigned short* T1 = Zb + NC;                    // [N,128] attn-o
    unsigned short* Rq = T1 + NC;                    // [N,384] qkv
    float* HAf = (float*)Rq;                         // [N,128] f32 ha_pre (aliases dead qkv)
    unsigned short* OUTb = Rq + 2 * NC;              // [N,128] bf16 combined out
    unsigned short* T2 = Rq + 3 * NC;                // [N,256] bf16
    float* Zf = (float*)(T2 + 2 * NC);               // [N,128] f32 h_pre / out2
    unsigned short* WB = (unsigned short*)(Zf + NC); // 491520 bf16 weights
    float* STATS = (float*)(WB + 491520);            // 3 sets x NREP x 256
    const size_t STSZ = (size_t)NREP * 256;
    float* SCOFF = STATS + 3 * STSZ;                 // 512 (layer)
    float* SCPE = SCOFF + 512;                       // 64 (pe)
    int* icnt = (int*)(SCPE + 64);
    int* irow = icnt + NN;
    int* ielist = irow + NN + 1;
    int* ipart = ielist + EE;

    const int EW16 = NN * 16 / 256;
    const float invn = 1.f / (float)NN;
    float* outF = (float*)d_out;

    // ---- CSR build ----
    hipMemsetAsync(icnt, 0, NN * sizeof(int), stream);
    hist_k<<<EE / 256, 256, 0, stream>>>(eidx, icnt);
    scan1_k<<<NN / 256, 256, 0, stream>>>(icnt, irow, ipart);
    scan2_k<<<1, 256, 0, stream>>>(ipart);
    scan3_k<<<NN / 256, 256, 0, stream>>>(irow, ipart);
    hipMemsetAsync(icnt, 0, NN * sizeof(int), stream);
    fill_k<<<EE / 256, 256, 0, stream>>>(eidx, irow, icnt, ielist);

    // ---- weights -> bf16 WT ----
    cvtw<<<491520 / 256, 256, 0, stream>>>(gine_W1, gine_W2, attn_inW, attn_outW, mlp_W1, mlp_W2, WB);

    // ---- input featurization ----
    hipMemsetAsync(STATS, 0, 64 * sizeof(float), stream);
    colstats_pe<<<NN / 256, 256, 0, stream>>>(pe, STATS);
    bn_finalize<<<1, 64, 0, stream>>>(STATS, pe_gamma, pe_beta, SCPE, 20, invn, 1);
    embed_b<<<EW16, 256, 0, stream>>>(node_type, pe, SCPE, pe_W, pe_b, node_emb, XB);

    const dim3 gB1(NN / 128, 1), gB2(NN / 128, 2), gB3(NN / 128, 3);
    const size_t LDS_B16 = 32768;
    const size_t LDS_F32 = 65536;
    for (int l = 0; l < LL; ++l) {
        unsigned short* WL = WB + (size_t)l * 163840;
        unsigned short* gW1T = WL;
        unsigned short* gW2T = WL + 16384;
        unsigned short* inWT = WL + 32768;
        unsigned short* oWT = WL + 81920;
        unsigned short* mW1T = WL + 98304;
        unsigned short* mW2T = WL + 131072;
        const float* gb1 = gine_b1 + (size_t)l * CC;
        const float* gb2 = gine_b2 + (size_t)l * CC;
        const float* inb = attn_inb + (size_t)l * 384;
        const float* ob = attn_outb + (size_t)l * CC;
        const float* mb1 = mlp_b1 + (size_t)l * 256;
        const float* mb2 = mlp_b2 + (size_t)l * CC;

        hipMemsetAsync(STATS, 0, 3 * STSZ * sizeof(float), stream);

        // ---- GINEConv (fused gather + MLP) ----
        gine_fused<<<NN / 128, 256, LDS_F32, stream>>>(XB, eidx, etype, edge_emb, irow, ielist,
                                                       gW1T, gb1, gW2T, gb2, Zf, STATS);
        bn_finalize<<<1, 128, 0, stream>>>(STATS, n1_g + l * CC, n1_b + l * CC, SCOFF, 128, invn, NREP);

        // ---- attention ----
        gemm_ls<0, 0, 0, 4, 0><<<gB3, 256, LDS_B16, stream>>>(XB, inWT, inb, nullptr, Rq, nullptr, 384);
        attn_mfma<<<BB * 2, 256, 0, stream>>>(Rq, T1);
        gemm_ls<0, 1, 1, 4, 1><<<gB1, 256, LDS_F32, stream>>>(T1, oWT, ob, XB, HAf, STATS + STSZ, 128);
        bn_finalize<<<1, 128, 0, stream>>>(STATS + STSZ, n2_g + l * CC, n2_b + l * CC, SCOFF + 256, 128, invn, NREP);

        // ---- combine + FFN ----
        combine2<<<EW16, 256, 0, stream>>>(Zf, HAf, SCOFF, OUTb);
        gemm_ls<1, 0, 0, 4, 0><<<gB2, 256, LDS_B16, stream>>>(OUTb, mW1T, mb1, nullptr, T2, nullptr, 256);
        gemm_ls<0, 1, 1, 8, 1><<<gB1, 256, LDS_F32, stream>>>(T2, mW2T, mb2, OUTb, Zf, STATS + 2 * STSZ, 128);
        bn_finalize<<<1, 128, 0, stream>>>(STATS + 2 * STSZ, n3_g + l * CC, n3_b + l * CC, SCOFF, 128, invn, NREP);
        if (l < LL - 1)
            bn_apply_b<<<EW16, 256, 0, stream>>>(Zf, SCOFF, XB);
        else
            bn_apply_f<<<EW16, 256, 0, stream>>>(Zf, SCOFF, outF);
    }
}

// Round 10
// 674.615 us; speedup vs baseline: 1.0912x; 1.0912x over previous
//
#include <hip/hip_runtime.h>
#include <hip/hip_bf16.h>

#define NN 65536
#define SS 128
#define CC 128
#define EE 262144
#define BB 512
#define LL 3
#define NREP 64

typedef __attribute__((ext_vector_type(8))) short bf16x8;
typedef __attribute__((ext_vector_type(4))) float f32x4;

__device__ __forceinline__ float b2f(unsigned short u) {
    union { unsigned int i; float f; } x; x.i = ((unsigned int)u) << 16; return x.f;
}
__device__ __forceinline__ unsigned short f2b(float f) {
    union { float f; unsigned int i; } x; x.f = f;
    unsigned int r = x.i + 0x7fffu + ((x.i >> 16) & 1u);
    return (unsigned short)(r >> 16);
}
// swizzled byte offset within a tile of row-stride ROWB bytes
#define SWB(row, colbyte, ROWB) ((row) * (ROWB) + ((colbyte) ^ (((row) & 7) << 4)))

// ================= CSR build =================
__global__ __launch_bounds__(256) void hist_k(const int* __restrict__ eidx, int* __restrict__ cnt) {
    const int e = blockIdx.x * 256 + threadIdx.x;
    atomicAdd(&cnt[eidx[EE + e]], 1);
}
__global__ __launch_bounds__(256) void scan1_k(const int* __restrict__ cnt, int* __restrict__ row,
                                               int* __restrict__ part) {
    __shared__ int s[256];
    const int tid = threadIdx.x;
    const int i = blockIdx.x * 256 + tid;
    const int v = cnt[i];
    s[tid] = v;
    __syncthreads();
    for (int off = 1; off < 256; off <<= 1) {
        int t = (tid >= off) ? s[tid - off] : 0;
        __syncthreads(); s[tid] += t; __syncthreads();
    }
    row[i] = s[tid] - v;
    if (tid == 255) part[blockIdx.x] = s[255];
}
__global__ __launch_bounds__(256) void scan2_k(int* __restrict__ part) {
    __shared__ int s[256];
    const int tid = threadIdx.x;
    const int v = part[tid];
    s[tid] = v;
    __syncthreads();
    for (int off = 1; off < 256; off <<= 1) {
        int t = (tid >= off) ? s[tid - off] : 0;
        __syncthreads(); s[tid] += t; __syncthreads();
    }
    part[tid] = s[tid] - v;
}
__global__ __launch_bounds__(256) void scan3_k(int* __restrict__ row, const int* __restrict__ part) {
    const int i = blockIdx.x * 256 + threadIdx.x;
    row[i] += part[blockIdx.x];
    if (i == 0) row[NN] = EE;
}
__global__ __launch_bounds__(256) void fill_k(const int* __restrict__ eidx, const int* __restrict__ row,
                                              int* __restrict__ cnt, int* __restrict__ elist) {
    const int e = blockIdx.x * 256 + threadIdx.x;
    const int d = eidx[EE + e];
    const int slot = row[d] + atomicAdd(&cnt[d], 1);
    elist[slot] = e;
}

// ================= weight convert + transpose to bf16 WT[N][K] =================
__global__ __launch_bounds__(256) void cvtw(const float* __restrict__ gW1, const float* __restrict__ gW2,
                                            const float* __restrict__ inW, const float* __restrict__ oW,
                                            const float* __restrict__ mW1, const float* __restrict__ mW2,
                                            unsigned short* __restrict__ WB) {
    const int g = blockIdx.x * 256 + threadIdx.x;  // 0 .. 3*163840
    const int l = g / 163840;
    const int r = g % 163840;
    const float* src; int K, Nc, dst, i;
    if (r < 16384)       { src = gW1 + l * 16384; K = 128; Nc = 128; dst = 0;      i = r; }
    else if (r < 32768)  { src = gW2 + l * 16384; K = 128; Nc = 128; dst = 16384;  i = r - 16384; }
    else if (r < 81920)  { src = inW + l * 49152; K = 128; Nc = 384; dst = 32768;  i = r - 32768; }
    else if (r < 98304)  { src = oW  + l * 16384; K = 128; Nc = 128; dst = 81920;  i = r - 81920; }
    else if (r < 131072) { src = mW1 + l * 32768; K = 128; Nc = 256; dst = 98304;  i = r - 98304; }
    else                 { src = mW2 + l * 32768; K = 256; Nc = 128; dst = 131072; i = r - 131072; }
    const int k = i / Nc, c = i % Nc;
    WB[(size_t)l * 163840 + dst + (size_t)c * K + k] = f2b(src[i]);
}

// ================= pe column stats: one row per thread =================
__global__ __launch_bounds__(256) void colstats_pe(const float* __restrict__ pe,
                                                   float* __restrict__ stats) {
    const int r = blockIdx.x * 256 + threadIdx.x;
    const float* p = pe + (size_t)r * 20;
    float v[20];
    *(float4*)&v[0]  = *(const float4*)(p);
    *(float4*)&v[4]  = *(const float4*)(p + 4);
    *(float4*)&v[8]  = *(const float4*)(p + 8);
    *(float4*)&v[12] = *(const float4*)(p + 12);
    *(float4*)&v[16] = *(const float4*)(p + 16);
    float s[20], q[20];
#pragma unroll
    for (int i = 0; i < 20; ++i) { s[i] = v[i]; q[i] = v[i] * v[i]; }
#pragma unroll
    for (int off = 1; off < 64; off <<= 1) {
#pragma unroll
        for (int i = 0; i < 20; ++i) {
            s[i] += __shfl_xor(s[i], off);
            q[i] += __shfl_xor(q[i], off);
        }
    }
    __shared__ float red[4][40];
    const int lane = threadIdx.x & 63, w = threadIdx.x >> 6;
    if (lane == 0) {
#pragma unroll
        for (int i = 0; i < 20; ++i) { red[w][i] = s[i]; red[w][20 + i] = q[i]; }
    }
    __syncthreads();
    if (threadIdx.x < 40) {
        const float t = red[0][threadIdx.x] + red[1][threadIdx.x] +
                        red[2][threadIdx.x] + red[3][threadIdx.x];
        atomicAdd(&stats[threadIdx.x], t);
    }
}

// ================= BN helpers =================
__global__ void bn_finalize(const float* __restrict__ stats, const float* __restrict__ g,
                            const float* __restrict__ b, float* __restrict__ scoff,
                            int ncols, float invn, int nrep) {
    const int c = threadIdx.x;
    if (c < ncols) {
        float s = 0.f, q = 0.f;
#pragma unroll 8
        for (int r = 0; r < nrep; ++r) {
            s += stats[r * 2 * ncols + c];
            q += stats[r * 2 * ncols + ncols + c];
        }
        float m = s * invn;
        float var = q * invn - m * m;
        float rs = rsqrtf(var + 1e-5f);
        float sc = g[c] * rs;
        scoff[c] = sc;
        scoff[ncols + c] = b[c] - m * sc;
    }
}
__global__ __launch_bounds__(256) void bn_apply_b(const float* __restrict__ in,
                                                  const float* __restrict__ scoff,
                                                  unsigned short* __restrict__ out) {
    const size_t g = (size_t)blockIdx.x * 256 + threadIdx.x;  // N*16
    const int c8 = ((int)g & 15) << 3;
    float4 a0 = *(const float4*)(in + g * 8);
    float4 a1 = *(const float4*)(in + g * 8 + 4);
    float v[8] = {a0.x, a0.y, a0.z, a0.w, a1.x, a1.y, a1.z, a1.w};
    union { uint4 u; unsigned short s[8]; } o;
#pragma unroll
    for (int i = 0; i < 8; ++i) o.s[i] = f2b(v[i] * scoff[c8 + i] + scoff[128 + c8 + i]);
    *(uint4*)(out + g * 8) = o.u;
}
__global__ __launch_bounds__(256) void bn_apply_f(const float* __restrict__ in,
                                                  const float* __restrict__ scoff,
                                                  float* __restrict__ out) {
    const size_t g = (size_t)blockIdx.x * 256 + threadIdx.x;
    const int c8 = ((int)g & 15) << 3;
    float4 a0 = *(const float4*)(in + g * 8);
    float4 a1 = *(const float4*)(in + g * 8 + 4);
    float v[8] = {a0.x, a0.y, a0.z, a0.w, a1.x, a1.y, a1.z, a1.w};
    float4 o0, o1;
    o0.x = v[0] * scoff[c8 + 0] + scoff[128 + c8 + 0];
    o0.y = v[1] * scoff[c8 + 1] + scoff[128 + c8 + 1];
    o0.z = v[2] * scoff[c8 + 2] + scoff[128 + c8 + 2];
    o0.w = v[3] * scoff[c8 + 3] + scoff[128 + c8 + 3];
    o1.x = v[4] * scoff[c8 + 4] + scoff[128 + c8 + 4];
    o1.y = v[5] * scoff[c8 + 5] + scoff[128 + c8 + 5];
    o1.z = v[6] * scoff[c8 + 6] + scoff[128 + c8 + 6];
    o1.w = v[7] * scoff[c8 + 7] + scoff[128 + c8 + 7];
    *(float4*)(out + g * 8) = o0;
    *(float4*)(out + g * 8 + 4) = o1;
}
__global__ __launch_bounds__(256) void combine2(const float* __restrict__ z,
                                                const float* __restrict__ ha,
                                                const float* __restrict__ scoff,
                                                unsigned short* __restrict__ out) {
    const size_t g = (size_t)blockIdx.x * 256 + threadIdx.x;
    const int c8 = ((int)g & 15) << 3;
    float4 a0 = *(const float4*)(z + g * 8);
    float4 a1 = *(const float4*)(z + g * 8 + 4);
    float4 b0 = *(const float4*)(ha + g * 8);
    float4 b1 = *(const float4*)(ha + g * 8 + 4);
    float va[8] = {a0.x, a0.y, a0.z, a0.w, a1.x, a1.y, a1.z, a1.w};
    float vb[8] = {b0.x, b0.y, b0.z, b0.w, b1.x, b1.y, b1.z, b1.w};
    union { uint4 u; unsigned short s[8]; } o;
#pragma unroll
    for (int i = 0; i < 8; ++i) {
        const int c = c8 + i;
        o.s[i] = f2b(va[i] * scoff[c] + scoff[128 + c] +
                     vb[i] * scoff[256 + c] + scoff[384 + c]);
    }
    *(uint4*)(out + g * 8) = o.u;
}

// ================= input featurization -> XB bf16 =================
__global__ __launch_bounds__(256) void embed_b(const int* __restrict__ node_type,
                                               const float* __restrict__ pe,
                                               const float* __restrict__ scoff,
                                               const float* __restrict__ peW,
                                               const float* __restrict__ peB,
                                               const float* __restrict__ node_emb,
                                               unsigned short* __restrict__ XB) {
    const int g = blockIdx.x * 256 + threadIdx.x;  // N*16
    const int n = g >> 4, c8 = (g & 15) << 3;
    float v[8];
    if (c8 < 120) {
        const float4 a = *(const float4*)(node_emb + (size_t)node_type[n] * 120 + c8);
        const float4 b = *(const float4*)(node_emb + (size_t)node_type[n] * 120 + c8 + 4);
        v[0] = a.x; v[1] = a.y; v[2] = a.z; v[3] = a.w;
        v[4] = b.x; v[5] = b.y; v[6] = b.z; v[7] = b.w;
    } else {
#pragma unroll
        for (int j = 0; j < 8; ++j) v[j] = peB[j];
#pragma unroll
        for (int k = 0; k < 20; ++k) {
            const float p = pe[(size_t)n * 20 + k] * scoff[k] + scoff[20 + k];
#pragma unroll
            for (int j = 0; j < 8; ++j) v[j] = fmaf(p, peW[k * 8 + j], v[j]);
        }
    }
    union { uint4 u; unsigned short s[8]; } o;
#pragma unroll
    for (int i = 0; i < 8; ++i) o.s[i] = f2b(v[i]);
    *(uint4*)(XB + (size_t)g * 8) = o.u;
}

// ================= GINE gather: Zb = X + sum relu(X[src]+ee)  (bf16) =================
__global__ __launch_bounds__(256) void gine_gather_b(const unsigned short* __restrict__ XB,
                                                     const int* __restrict__ eidx,
                                                     const int* __restrict__ etype,
                                                     const float* __restrict__ edge_emb,
                                                     const int* __restrict__ row,
                                                     const int* __restrict__ elist,
                                                     unsigned short* __restrict__ Z) {
    const int n = blockIdx.x * 16 + (threadIdx.x >> 4);
    const int c8 = (threadIdx.x & 15) << 3;
    const int beg = row[n], end = row[n + 1];
    union { uint4 u; unsigned short s[8]; } x;
    x.u = *(const uint4*)(XB + (size_t)n * 128 + c8);
    float z[8];
#pragma unroll
    for (int i = 0; i < 8; ++i) z[i] = b2f(x.s[i]);
    for (int j = beg; j < end; ++j) {
        const int e = elist[j];
        const int s = eidx[e];
        const int et = etype[e];
        union { uint4 u; unsigned short s[8]; } xs;
        xs.u = *(const uint4*)(XB + (size_t)s * 128 + c8);
        const float4 e0 = *(const float4*)(edge_emb + (size_t)et * 128 + c8);
        const float4 e1 = *(const float4*)(edge_emb + (size_t)et * 128 + c8 + 4);
        z[0] += fmaxf(b2f(xs.s[0]) + e0.x, 0.f);
        z[1] += fmaxf(b2f(xs.s[1]) + e0.y, 0.f);
        z[2] += fmaxf(b2f(xs.s[2]) + e0.z, 0.f);
        z[3] += fmaxf(b2f(xs.s[3]) + e0.w, 0.f);
        z[4] += fmaxf(b2f(xs.s[4]) + e1.x, 0.f);
        z[5] += fmaxf(b2f(xs.s[5]) + e1.y, 0.f);
        z[6] += fmaxf(b2f(xs.s[6]) + e1.z, 0.f);
        z[7] += fmaxf(b2f(xs.s[7]) + e1.w, 0.f);
    }
    union { uint4 u; unsigned short s[8]; } o;
#pragma unroll
    for (int i = 0; i < 8; ++i) o.s[i] = f2b(z[i]);
    *(uint4*)(Z + (size_t)n * 128 + c8) = o.u;
}

// ====== fused GINE MLP (no gather): h_pre = relu(Zb@W1+b1)@W2 + b2 + X -> f32 + stats ======
// Block = 128 rows, 4 waves, 64KB LDS: slotB (B1/B2 swz) | slotT (t1 swz); f32 out-stage 64KB.
__global__ __launch_bounds__(256) void gine_mlp(const unsigned short* __restrict__ Zb,
                                                const unsigned short* __restrict__ XB,
                                                const unsigned short* __restrict__ W1T,
                                                const float* __restrict__ b1,
                                                const unsigned short* __restrict__ W2T,
                                                const float* __restrict__ b2,
                                                float* __restrict__ outp,
                                                float* __restrict__ stats) {
    extern __shared__ __align__(16) char LDSX[];
    char* slotB = LDSX;            // 32KB
    char* slotT = LDSX + 32768;    // 32KB
    const int tid = threadIdx.x, lane = tid & 63, w = tid >> 6;
    const int lr = lane & 15, lg = lane >> 4;
    const int bm = blockIdx.x * 128;

#pragma unroll
    for (int i = 0; i < 8; ++i) {
        const int c = (i * 256 + tid) * 16;
        const int row = c >> 8, inrow = c & 255;
        *(uint4*)(slotB + SWB(row, inrow, 256)) = *(const uint4*)(W1T + (size_t)row * 128 + (inrow >> 1));
    }
    bf16x8 af1[2][4];
#pragma unroll
    for (int r = 0; r < 2; ++r)
#pragma unroll
        for (int ks = 0; ks < 4; ++ks)
            af1[r][ks] = *(const bf16x8*)(Zb + (size_t)(bm + w * 32 + r * 16 + lr) * 128 + ks * 32 + lg * 8);
    float bc1[8];
#pragma unroll
    for (int nt = 0; nt < 8; ++nt) bc1[nt] = b1[nt * 16 + lr];
    __syncthreads();

    f32x4 acc[2][8];
#pragma unroll
    for (int r = 0; r < 2; ++r)
#pragma unroll
        for (int nt = 0; nt < 8; ++nt) acc[r][nt] = (f32x4){0.f, 0.f, 0.f, 0.f};
#pragma unroll
    for (int ks = 0; ks < 4; ++ks) {
        bf16x8 bq[8];
#pragma unroll
        for (int nt = 0; nt < 8; ++nt)
            bq[nt] = *(const bf16x8*)(slotB + SWB(nt * 16 + lr, ks * 64 + lg * 16, 256));
#pragma unroll
        for (int r = 0; r < 2; ++r)
#pragma unroll
            for (int nt = 0; nt < 8; ++nt)
                acc[r][nt] = __builtin_amdgcn_mfma_f32_16x16x32_bf16(af1[r][ks], bq[nt], acc[r][nt], 0, 0, 0);
    }
#pragma unroll
    for (int r = 0; r < 2; ++r)
#pragma unroll
        for (int nt = 0; nt < 8; ++nt)
#pragma unroll
            for (int j = 0; j < 4; ++j) {
                const float v = fmaxf(acc[r][nt][j] + bc1[nt], 0.f);
                *(unsigned short*)(slotT + SWB(w * 32 + r * 16 + lg * 4 + j, (nt * 16 + lr) * 2, 256)) = f2b(v);
            }
    __syncthreads();
#pragma unroll
    for (int i = 0; i < 8; ++i) {
        const int c = (i * 256 + tid) * 16;
        const int row = c >> 8, inrow = c & 255;
        *(uint4*)(slotB + SWB(row, inrow, 256)) = *(const uint4*)(W2T + (size_t)row * 128 + (inrow >> 1));
    }
    bf16x8 af2[2][4];
#pragma unroll
    for (int r = 0; r < 2; ++r)
#pragma unroll
        for (int ks = 0; ks < 4; ++ks)
            af2[r][ks] = *(const bf16x8*)(slotT + SWB(w * 32 + r * 16 + lr, ks * 64 + lg * 16, 256));
    float bc2[8];
#pragma unroll
    for (int nt = 0; nt < 8; ++nt) bc2[nt] = b2[nt * 16 + lr];
    __syncthreads();

#pragma unroll
    for (int r = 0; r < 2; ++r)
#pragma unroll
        for (int nt = 0; nt < 8; ++nt) acc[r][nt] = (f32x4){0.f, 0.f, 0.f, 0.f};
#pragma unroll
    for (int ks = 0; ks < 4; ++ks) {
        bf16x8 bq[8];
#pragma unroll
        for (int nt = 0; nt < 8; ++nt)
            bq[nt] = *(const bf16x8*)(slotB + SWB(nt * 16 + lr, ks * 64 + lg * 16, 256));
#pragma unroll
        for (int r = 0; r < 2; ++r)
#pragma unroll
            for (int nt = 0; nt < 8; ++nt)
                acc[r][nt] = __builtin_amdgcn_mfma_f32_16x16x32_bf16(af2[r][ks], bq[nt], acc[r][nt], 0, 0, 0);
    }
    __syncthreads();

#pragma unroll
    for (int r = 0; r < 2; ++r)
#pragma unroll
        for (int nt = 0; nt < 8; ++nt)
#pragma unroll
            for (int j = 0; j < 4; ++j)
                ((float*)LDSX)[(w * 32 + r * 16 + lg * 4 + j) * 128 + nt * 16 + lr] = acc[r][nt][j] + bc2[nt];
    __syncthreads();

    float ssum[4] = {0.f, 0.f, 0.f, 0.f}, ssq[4] = {0.f, 0.f, 0.f, 0.f};
#pragma unroll
    for (int i = 0; i < 16; ++i) {
        const int L = (i * 256 + tid) * 16;
        const int row = L >> 9, col = (L & 511) >> 2;
        float4 v = *(const float4*)(LDSX + L);
        const uint2 rv = *(const uint2*)(XB + (size_t)(bm + row) * 128 + col);
        v.x += b2f((unsigned short)(rv.x & 0xffffu));
        v.y += b2f((unsigned short)(rv.x >> 16));
        v.z += b2f((unsigned short)(rv.y & 0xffffu));
        v.w += b2f((unsigned short)(rv.y >> 16));
        ssum[0] += v.x; ssq[0] += v.x * v.x;
        ssum[1] += v.y; ssq[1] += v.y * v.y;
        ssum[2] += v.z; ssq[2] += v.z * v.z;
        ssum[3] += v.w; ssq[3] += v.w * v.w;
        *(float4*)(outp + (size_t)(bm + row) * 128 + col) = v;
    }
#pragma unroll
    for (int c2 = 0; c2 < 4; ++c2) {
        ssum[c2] += __shfl_xor(ssum[c2], 32);
        ssq[c2]  += __shfl_xor(ssq[c2], 32);
    }
    if (lane < 32) {
        float* st = stats + (size_t)(blockIdx.x & (NREP - 1)) * 256;
        const int c0 = (lane & 31) * 4;
#pragma unroll
        for (int c2 = 0; c2 < 4; ++c2) {
            atomicAdd(&st[c0 + c2], ssum[c2]);
            atomicAdd(&st[128 + c0 + c2], ssq[c2]);
        }
    }
}

// ====== attention megakernel: one block per graph (128 rows, 512 thr, 8 waves) ======
// XB -> qkv (LDS) -> 2-head attention -> O@Wout^T + X + stats -> HA (f32)
// LDS 128KB: OQ[2][128][64]sw128 (Q->O) | KS[2][128][64]sw128 | VT[2][64][128]sw256 | WS 32KB (W->P->Wout)
__global__ __launch_bounds__(512) void attn_mega(const unsigned short* __restrict__ XB,
                                                 const unsigned short* __restrict__ inWT,
                                                 const float* __restrict__ inb,
                                                 const unsigned short* __restrict__ oWT,
                                                 const float* __restrict__ ob,
                                                 float* __restrict__ HA,
                                                 float* __restrict__ stats) {
    extern __shared__ __align__(16) char SM[];
    __shared__ float inv2[2][128];
    const int OQ = 0, KSo = 32768, VTo = 65536, WSo = 98304;
    const int tid = threadIdx.x, lane = tid & 63, w = tid >> 6;      // w: 0..7
    const int lr = lane & 15, lg = (lane >> 4) & 3;
    const int bm = blockIdx.x * 128;

    // X fragments (rows w*16+lr)
    bf16x8 af[4];
#pragma unroll
    for (int ks = 0; ks < 4; ++ks)
        af[ks] = *(const bf16x8*)(XB + (size_t)(bm + w * 16 + lr) * 128 + ks * 32 + lg * 8);

    // ---- QKV: 3 chunks of 128 cols ----
    for (int c = 0; c < 3; ++c) {
        __syncthreads();
#pragma unroll
        for (int i = 0; i < 4; ++i) {
            const int byte = (i * 512 + tid) * 16;
            const int row = byte >> 8, inrow = byte & 255;
            *(uint4*)(SM + WSo + SWB(row, inrow, 256)) =
                *(const uint4*)(inWT + (size_t)(c * 128 + row) * 128 + (inrow >> 1));
        }
        __syncthreads();
        float bc[8];
#pragma unroll
        for (int nt = 0; nt < 8; ++nt) bc[nt] = inb[c * 128 + nt * 16 + lr];
        f32x4 acc[8];
#pragma unroll
        for (int nt = 0; nt < 8; ++nt) acc[nt] = (f32x4){0.f, 0.f, 0.f, 0.f};
#pragma unroll
        for (int ks = 0; ks < 4; ++ks) {
            bf16x8 bq[8];
#pragma unroll
            for (int nt = 0; nt < 8; ++nt)
                bq[nt] = *(const bf16x8*)(SM + WSo + SWB(nt * 16 + lr, ks * 64 + lg * 16, 256));
#pragma unroll
            for (int nt = 0; nt < 8; ++nt)
                acc[nt] = __builtin_amdgcn_mfma_f32_16x16x32_bf16(af[ks], bq[nt], acc[nt], 0, 0, 0);
        }
        if (c < 2) {
            const int slot = (c == 0) ? OQ : KSo;
#pragma unroll
            for (int nt = 0; nt < 8; ++nt) {
                const int col = nt * 16 + lr, h = col >> 6, d = col & 63;
#pragma unroll
                for (int j = 0; j < 4; ++j) {
                    const int q = w * 16 + lg * 4 + j;
                    *(unsigned short*)(SM + slot + h * 16384 + SWB(q, d * 2, 128)) = f2b(acc[nt][j] + bc[nt]);
                }
            }
        } else {
#pragma unroll
            for (int nt = 0; nt < 8; ++nt) {
                const int col = nt * 16 + lr, h = col >> 6, d = col & 63;
#pragma unroll
                for (int j = 0; j < 4; ++j) {
                    const int k = w * 16 + lg * 4 + j;
                    *(unsigned short*)(SM + VTo + h * 16384 + SWB(d, k * 2, 256)) = f2b(acc[nt][j] + bc[nt]);
                }
            }
        }
    }
    __syncthreads();

    // ---- attention (per head; all inter-op deps are wave-private rows -> no barriers) ----
    const float SC = 0.125f * 1.44269504f;
    for (int h = 0; h < 2; ++h) {
        f32x4 s[8];
#pragma unroll
        for (int m = 0; m < 8; ++m) s[m] = (f32x4){0.f, 0.f, 0.f, 0.f};
#pragma unroll
        for (int kd = 0; kd < 2; ++kd) {
            bf16x8 ak[8];
#pragma unroll
            for (int m = 0; m < 8; ++m)
                ak[m] = *(const bf16x8*)(SM + KSo + h * 16384 + SWB(m * 16 + lr, kd * 64 + lg * 16, 128));
            const bf16x8 bq = *(const bf16x8*)(SM + OQ + h * 16384 + SWB(w * 16 + lr, kd * 64 + lg * 16, 128));
#pragma unroll
            for (int m = 0; m < 8; ++m)
                s[m] = __builtin_amdgcn_mfma_f32_16x16x32_bf16(ak[m], bq, s[m], 0, 0, 0);
        }
        float mx = -1e30f;
#pragma unroll
        for (int m = 0; m < 8; ++m)
#pragma unroll
            for (int j = 0; j < 4; ++j) { s[m][j] *= SC; mx = fmaxf(mx, s[m][j]); }
        mx = fmaxf(mx, __shfl_xor(mx, 16));
        mx = fmaxf(mx, __shfl_xor(mx, 32));
        float sum = 0.f;
#pragma unroll
        for (int m = 0; m < 8; ++m)
#pragma unroll
            for (int j = 0; j < 4; ++j) {
                const float p = exp2f(s[m][j] - mx);
                s[m][j] = p;
                sum += p;
            }
        sum += __shfl_xor(sum, 16);
        sum += __shfl_xor(sum, 32);
        if (lg == 0) inv2[h][w * 16 + lr] = 1.0f / sum;
        {   // P[q][key] -> WS (own q rows only)
            const int q = w * 16 + lr;
#pragma unroll
            for (int m = 0; m < 8; ++m) {
                ushort4 pk;
                pk.x = f2b(s[m][0]); pk.y = f2b(s[m][1]); pk.z = f2b(s[m][2]); pk.w = f2b(s[m][3]);
                *(ushort4*)(SM + WSo + SWB(q, (m * 16 + lg * 4) * 2, 256)) = pk;
            }
        }
        // PV
        f32x4 o[4];
#pragma unroll
        for (int n = 0; n < 4; ++n) o[n] = (f32x4){0.f, 0.f, 0.f, 0.f};
#pragma unroll
        for (int ks = 0; ks < 4; ++ks) {
            const bf16x8 ap = *(const bf16x8*)(SM + WSo + SWB(w * 16 + lr, ks * 64 + lg * 16, 256));
            bf16x8 bv[4];
#pragma unroll
            for (int n = 0; n < 4; ++n)
                bv[n] = *(const bf16x8*)(SM + VTo + h * 16384 + SWB(n * 16 + lr, ks * 64 + lg * 16, 256));
#pragma unroll
            for (int n = 0; n < 4; ++n)
                o[n] = __builtin_amdgcn_mfma_f32_16x16x32_bf16(ap, bv[n], o[n], 0, 0, 0);
        }
        // O (scaled) overwrites this head's Q (own q rows only)
#pragma unroll
        for (int n = 0; n < 4; ++n) {
            const int d = n * 16 + lr;
#pragma unroll
            for (int j = 0; j < 4; ++j) {
                const int q = w * 16 + lg * 4 + j;
                *(unsigned short*)(SM + OQ + h * 16384 + SWB(q, d * 2, 128)) = f2b(o[n][j] * inv2[h][q]);
            }
        }
    }
    __syncthreads();

    // ---- out projection: HA = O @ Wout^T + ob + X, stats ----
#pragma unroll
    for (int i = 0; i < 4; ++i) {
        const int byte = (i * 512 + tid) * 16;
        const int row = byte >> 8, inrow = byte & 255;
        *(uint4*)(SM + WSo + SWB(row, inrow, 256)) = *(const uint4*)(oWT + (size_t)row * 128 + (inrow >> 1));
    }
    bf16x8 afo[4];
#pragma unroll
    for (int ks = 0; ks < 4; ++ks)
        afo[ks] = *(const bf16x8*)(SM + OQ + (ks >> 1) * 16384 +
                                   SWB(w * 16 + lr, ((ks & 1) * 32 + lg * 8) * 2, 128));
    __syncthreads();
    float bco[8];
#pragma unroll
    for (int nt = 0; nt < 8; ++nt) bco[nt] = ob[nt * 16 + lr];
    f32x4 acc[8];
#pragma unroll
    for (int nt = 0; nt < 8; ++nt) acc[nt] = (f32x4){0.f, 0.f, 0.f, 0.f};
#pragma unroll
    for (int ks = 0; ks < 4; ++ks) {
        bf16x8 bq[8];
#pragma unroll
        for (int nt = 0; nt < 8; ++nt)
            bq[nt] = *(const bf16x8*)(SM + WSo + SWB(nt * 16 + lr, ks * 64 + lg * 16, 256));
#pragma unroll
        for (int nt = 0; nt < 8; ++nt)
            acc[nt] = __builtin_amdgcn_mfma_f32_16x16x32_bf16(afo[ks], bq[nt], acc[nt], 0, 0, 0);
    }
    // stage f32 out into KSo..(+64KB) (K and V^T dead)
    float* F = (float*)(SM + KSo);
#pragma unroll
    for (int nt = 0; nt < 8; ++nt)
#pragma unroll
        for (int j = 0; j < 4; ++j)
            F[(w * 16 + lg * 4 + j) * 128 + nt * 16 + lr] = acc[nt][j] + bco[nt];
    __syncthreads();
    float ssum[4] = {0.f, 0.f, 0.f, 0.f}, ssq[4] = {0.f, 0.f, 0.f, 0.f};
#pragma unroll
    for (int i = 0; i < 8; ++i) {
        const int L = (i * 512 + tid) * 16;
        const int row = L >> 9, col = (L & 511) >> 2;
        float4 v = *(const float4*)(SM + KSo + L);
        const uint2 rv = *(const uint2*)(XB + (size_t)(bm + row) * 128 + col);
        v.x += b2f((unsigned short)(rv.x & 0xffffu));
        v.y += b2f((unsigned short)(rv.x >> 16));
        v.z += b2f((unsigned short)(rv.y & 0xffffu));
        v.w += b2f((unsigned short)(rv.y >> 16));
        ssum[0] += v.x; ssq[0] += v.x * v.x;
        ssum[1] += v.y; ssq[1] += v.y * v.y;
        ssum[2] += v.z; ssq[2] += v.z * v.z;
        ssum[3] += v.w; ssq[3] += v.w * v.w;
        *(float4*)(HA + (size_t)(bm + row) * 128 + col) = v;
    }
#pragma unroll
    for (int c2 = 0; c2 < 4; ++c2) {
        ssum[c2] += __shfl_xor(ssum[c2], 32);
        ssq[c2]  += __shfl_xor(ssq[c2], 32);
    }
    if (lane < 32) {
        float* st = stats + (size_t)(blockIdx.x & (NREP - 1)) * 256;
        const int c0 = (lane & 31) * 4;
#pragma unroll
        for (int c2 = 0; c2 < 4; ++c2) {
            atomicAdd(&st[c0 + c2], ssum[c2]);
            atomicAdd(&st[128 + c0 + c2], ssq[c2]);
        }
    }
}

// ====== LDS-store GEMM: out[M,Nw] = act(A[M,K] @ WT[Nw,K]^T + bias [+resid]) ======
template <int RELU, int RESID, int STATS, int KS, int OUTF>
__global__ __launch_bounds__(256) void gemm_ls(const unsigned short* __restrict__ A,
                                               const unsigned short* __restrict__ WT,
                                               const float* __restrict__ bias,
                                               const unsigned short* __restrict__ resid,
                                               void* __restrict__ outp,
                                               float* __restrict__ stats, int Nw) {
    extern __shared__ __align__(16) char LDSX[];
    const int K = KS * 32;
    const int ROWB = K * 2;
    const int tid = threadIdx.x, lane = tid & 63, w = tid >> 6;
    const int lr = lane & 15, lg = lane >> 4;
    const int bm = blockIdx.x * 128;
    const int bn = blockIdx.y * 128;

#pragma unroll
    for (int i = 0; i < K / 16; ++i) {
        const int c = (i * 256 + tid) * 16;
        const int row = c / ROWB, inrow = c % ROWB;
        *(uint4*)(LDSX + SWB(row, inrow, ROWB)) =
            *(const uint4*)(WT + (size_t)(bn + row) * K + (inrow >> 1));
    }
    bf16x8 af[2][KS];
#pragma unroll
    for (int r = 0; r < 2; ++r)
#pragma unroll
        for (int ks = 0; ks < KS; ++ks)
            af[r][ks] = *(const bf16x8*)(A + (size_t)(bm + w * 32 + r * 16 + lr) * K + ks * 32 + lg * 8);
    float bcol[8];
#pragma unroll
    for (int nt = 0; nt < 8; ++nt) bcol[nt] = bias[bn + nt * 16 + lr];
    __syncthreads();

    f32x4 acc[2][8];
#pragma unroll
    for (int r = 0; r < 2; ++r)
#pragma unroll
        for (int nt = 0; nt < 8; ++nt) acc[r][nt] = (f32x4){0.f, 0.f, 0.f, 0.f};
#pragma unroll
    for (int ks = 0; ks < KS; ++ks) {
        bf16x8 bq[8];
#pragma unroll
        for (int nt = 0; nt < 8; ++nt)
            bq[nt] = *(const bf16x8*)(LDSX + SWB(nt * 16 + lr, ks * 64 + lg * 16, ROWB));
#pragma unroll
        for (int r = 0; r < 2; ++r)
#pragma unroll
            for (int nt = 0; nt < 8; ++nt)
                acc[r][nt] = __builtin_amdgcn_mfma_f32_16x16x32_bf16(af[r][ks], bq[nt], acc[r][nt], 0, 0, 0);
    }
    __syncthreads();

#pragma unroll
    for (int r = 0; r < 2; ++r)
#pragma unroll
        for (int nt = 0; nt < 8; ++nt)
#pragma unroll
            for (int j = 0; j < 4; ++j) {
                float v = acc[r][nt][j] + bcol[nt];
                if (RELU) v = fmaxf(v, 0.f);
                const int rl = w * 32 + r * 16 + lg * 4 + j;
                const int col = nt * 16 + lr;
                if (OUTF) ((float*)LDSX)[rl * 128 + col] = v;
                else ((unsigned short*)LDSX)[rl * 128 + col] = f2b(v);
            }
    __syncthreads();

    if (OUTF) {
        float ssum[4] = {0.f, 0.f, 0.f, 0.f}, ssq[4] = {0.f, 0.f, 0.f, 0.f};
#pragma unroll
        for (int i = 0; i < 16; ++i) {
            const int L = (i * 256 + tid) * 16;
            const int row = L >> 9, col = (L & 511) >> 2;
            float4 v = *(const float4*)(LDSX + L);
            if (RESID) {
                const uint2 rv = *(const uint2*)(resid + (size_t)(bm + row) * Nw + bn + col);
                v.x += b2f((unsigned short)(rv.x & 0xffffu));
                v.y += b2f((unsigned short)(rv.x >> 16));
                v.z += b2f((unsigned short)(rv.y & 0xffffu));
                v.w += b2f((unsigned short)(rv.y >> 16));
            }
            if (STATS) {
                ssum[0] += v.x; ssq[0] += v.x * v.x;
                ssum[1] += v.y; ssq[1] += v.y * v.y;
                ssum[2] += v.z; ssq[2] += v.z * v.z;
                ssum[3] += v.w; ssq[3] += v.w * v.w;
            }
            *(float4*)((float*)outp + (size_t)(bm + row) * Nw + bn + col) = v;
        }
        if (STATS) {
#pragma unroll
            for (int c2 = 0; c2 < 4; ++c2) {
                ssum[c2] += __shfl_xor(ssum[c2], 32);
                ssq[c2]  += __shfl_xor(ssq[c2], 32);
            }
            if (lane < 32) {
                float* st = stats + (size_t)(blockIdx.x & (NREP - 1)) * 256;
                const int c0 = (lane & 31) * 4;
#pragma unroll
                for (int c2 = 0; c2 < 4; ++c2) {
                    atomicAdd(&st[c0 + c2], ssum[c2]);
                    atomicAdd(&st[128 + c0 + c2], ssq[c2]);
                }
            }
        }
    } else {
#pragma unroll
        for (int i = 0; i < 8; ++i) {
            const int L = (i * 256 + tid) * 16;
            const int row = L >> 8, colb = L & 255;
            *(uint4*)((char*)outp + ((size_t)(bm + row) * Nw + bn) * 2 + colb) = *(const uint4*)(LDSX + L);
        }
    }
}

extern "C" void kernel_launch(void* const* d_in, const int* in_sizes, int n_in,
                              void* d_out, int out_size, void* d_ws, size_t ws_size,
                              hipStream_t stream) {
    const int* node_type = (const int*)d_in[0];
    const float* pe = (const float*)d_in[1];
    const int* eidx = (const int*)d_in[2];
    const int* etype = (const int*)d_in[3];
    const float* pe_gamma = (const float*)d_in[5];
    const float* pe_beta = (const float*)d_in[6];
    const float* pe_W = (const float*)d_in[7];
    const float* pe_b = (const float*)d_in[8];
    const float* node_emb = (const float*)d_in[9];
    const float* edge_emb = (const float*)d_in[10];
    const float* gine_W1 = (const float*)d_in[11];
    const float* gine_b1 = (const float*)d_in[12];
    const float* gine_W2 = (const float*)d_in[13];
    const float* gine_b2 = (const float*)d_in[14];
    const float* n1_g = (const float*)d_in[15];
    const float* n1_b = (const float*)d_in[16];
    const float* n2_g = (const float*)d_in[17];
    const float* n2_b = (const float*)d_in[18];
    const float* n3_g = (const float*)d_in[19];
    const float* n3_b = (const float*)d_in[20];
    const float* attn_inW = (const float*)d_in[21];
    const float* attn_inb = (const float*)d_in[22];
    const float* attn_outW = (const float*)d_in[23];
    const float* attn_outb = (const float*)d_in[24];
    const float* mlp_W1 = (const float*)d_in[25];
    const float* mlp_b1 = (const float*)d_in[26];
    const float* mlp_W2 = (const float*)d_in[27];
    const float* mlp_b2 = (const float*)d_in[28];

    const size_t NC = (size_t)NN * CC;
    unsigned short* XB = (unsigned short*)d_ws;      // [N,128] bf16 backbone
    unsigned short* Zb = XB + NC;                    // [N,128] gather out
    unsigned short* T1 = Zb + NC;                    // (spare)
    unsigned short* Rq = T1 + NC;                    // region reused:
    float* HAf = (float*)Rq;                         //   [N,128] f32 ha_pre
    unsigned short* OUTb = Rq + 2 * NC;              // [N,128] bf16 combined out
    unsigned short* T2 = Rq + 3 * NC;                // [N,256] bf16
    float* Zf = (float*)(T2 + 2 * NC);               // [N,128] f32 h_pre / out2
    unsigned short* WB = (unsigned short*)(Zf + NC); // 491520 bf16 weights
    float* STATS = (float*)(WB + 491520);            // 3 sets x NREP x 256
    const size_t STSZ = (size_t)NREP * 256;
    float* SCOFF = STATS + 3 * STSZ;                 // 512 (layer)
    float* SCPE = SCOFF + 512;                       // 64 (pe)
    int* icnt = (int*)(SCPE + 64);
    int* irow = icnt + NN;
    int* ielist = irow + NN + 1;
    int* ipart = ielist + EE;

    const int EW16 = NN * 16 / 256;
    const float invn = 1.f / (float)NN;
    float* outF = (float*)d_out;

    // ---- CSR build ----
    hipMemsetAsync(icnt, 0, NN * sizeof(int), stream);
    hist_k<<<EE / 256, 256, 0, stream>>>(eidx, icnt);
    scan1_k<<<NN / 256, 256, 0, stream>>>(icnt, irow, ipart);
    scan2_k<<<1, 256, 0, stream>>>(ipart);
    scan3_k<<<NN / 256, 256, 0, stream>>>(irow, ipart);
    hipMemsetAsync(icnt, 0, NN * sizeof(int), stream);
    fill_k<<<EE / 256, 256, 0, stream>>>(eidx, irow, icnt, ielist);

    // ---- weights -> bf16 WT ----
    cvtw<<<491520 / 256, 256, 0, stream>>>(gine_W1, gine_W2, attn_inW, attn_outW, mlp_W1, mlp_W2, WB);

    // ---- input featurization ----
    hipMemsetAsync(STATS, 0, 64 * sizeof(float), stream);
    colstats_pe<<<NN / 256, 256, 0, stream>>>(pe, STATS);
    bn_finalize<<<1, 64, 0, stream>>>(STATS, pe_gamma, pe_beta, SCPE, 20, invn, 1);
    embed_b<<<EW16, 256, 0, stream>>>(node_type, pe, SCPE, pe_W, pe_b, node_emb, XB);

    const dim3 gB1(NN / 128, 1), gB2(NN / 128, 2);
    const size_t LDS_B16 = 32768;
    const size_t LDS_F32 = 65536;
    const size_t LDS_MEGA = 131072;
    for (int l = 0; l < LL; ++l) {
        unsigned short* WL = WB + (size_t)l * 163840;
        unsigned short* gW1T = WL;
        unsigned short* gW2T = WL + 16384;
        unsigned short* inWT = WL + 32768;
        unsigned short* oWT = WL + 81920;
        unsigned short* mW1T = WL + 98304;
        unsigned short* mW2T = WL + 131072;
        const float* gb1 = gine_b1 + (size_t)l * CC;
        const float* gb2 = gine_b2 + (size_t)l * CC;
        const float* inb = attn_inb + (size_t)l * 384;
        const float* ob = attn_outb + (size_t)l * CC;
        const float* mb1 = mlp_b1 + (size_t)l * 256;
        const float* mb2 = mlp_b2 + (size_t)l * CC;

        hipMemsetAsync(STATS, 0, 3 * STSZ * sizeof(float), stream);

        // ---- GINEConv: gather (high occupancy) + fused 2-GEMM MLP ----
        gine_gather_b<<<NN / 16, 256, 0, stream>>>(XB, eidx, etype, edge_emb, irow, ielist, Zb);
        gine_mlp<<<NN / 128, 256, LDS_F32, stream>>>(Zb, XB, gW1T, gb1, gW2T, gb2, Zf, STATS);
        bn_finalize<<<1, 128, 0, stream>>>(STATS, n1_g + l * CC, n1_b + l * CC, SCOFF, 128, invn, NREP);

        // ---- attention megakernel (qkv + 2-head attn + out-proj + resid + stats) ----
        attn_mega<<<BB, 512, LDS_MEGA, stream>>>(XB, inWT, inb, oWT, ob, HAf, STATS + STSZ);
        bn_finalize<<<1, 128, 0, stream>>>(STATS + STSZ, n2_g + l * CC, n2_b + l * CC, SCOFF + 256, 128, invn, NREP);

        // ---- combine + FFN ----
        combine2<<<EW16, 256, 0, stream>>>(Zf, HAf, SCOFF, OUTb);
        gemm_ls<1, 0, 0, 4, 0><<<gB2, 256, LDS_B16, stream>>>(OUTb, mW1T, mb1, nullptr, T2, nullptr, 256);
        gemm_ls<0, 1, 1, 8, 1><<<gB1, 256, LDS_F32, stream>>>(T2, mW2T, mb2, OUTb, Zf, STATS + 2 * STSZ, 128);
        bn_finalize<<<1, 128, 0, stream>>>(STATS + 2 * STSZ, n3_g + l * CC, n3_b + l * CC, SCOFF, 128, invn, NREP);
        if (l < LL - 1)
            bn_apply_b<<<EW16, 256, 0, stream>>>(Zf, SCOFF, XB);
        else
            bn_apply_f<<<EW16, 256, 0, stream>>>(Zf, SCOFF, outF);
    }
}